// Round 4
// baseline (12570.461 us; speedup 1.0000x reference)
//
#include <hip/hip_runtime.h>
#include <math.h>

#define RI __restrict__

namespace {

constexpr int Hn=512, En=512, Vn=10000, Fn=1280, Pn=196, Bn=32, Tn=80;
constexpr int G4 = 2048, KX = 1792;
constexpr int NCAT = 13888;          // 512 hid + 1280 gate + 2048 xp + 10048 logits(pad)
constexpr int NVT = 157;
constexpr int J_GATE = 512, J_XP = 1792, J_LOG = 3840;

// ---- workspace layout (float indices) ----
constexpr long O_ENC  = 0;                           // [B*P][H]
constexpr long O_W2T  = O_ENC  + (long)Bn*Pn*Hn;     // [F][H]
constexpr long O_WCAT = O_W2T  + (long)Fn*Hn;        // [512][NCAT] (w1T|gwT|whhT|owT)
constexpr long O_WIHT = O_WCAT + (long)Hn*NCAT;      // [KX][2048] permuted cols (pc=i*4+g)
constexpr long O_H    = O_WIHT + (long)KX*G4;        // [B][H]
constexpr long O_HT   = O_H    + (long)Bn*Hn;        // [H][B]
constexpr long O_C    = O_HT   + (long)Hn*Bn;        // [B][H]
constexpr long O_HID  = O_C    + (long)Bn*Hn;        // [B][H]
constexpr long O_GT   = O_HID  + (long)Bn*Hn;        // [F][B]
constexpr long O_XPT  = O_GT   + (long)Fn*Bn;        // [2048 pc][B]
constexpr long O_XT   = O_XPT  + (long)G4*Bn;        // [KX][B]
constexpr long O_PMV  = O_XT   + (long)KX*Bn;        // [B][157]
constexpr long O_PMI  = O_PMV  + (long)Bn*NVT;       // [B][157] int
// setup-only aliases inside O_ENC (consumed before k_encproj overwrites)
constexpr long O_IHCT  = O_ENC;                      // [1280][1024] (ihwT|icwT)
constexpr long O_MEANT = O_ENC + (long)Fn*1024;      // [F][B]

__device__ __forceinline__ float sigm(float x){ return 1.0f/(1.0f+expf(-x)); }
__device__ __forceinline__ void fma4(float4& a, const float4 x, const float w){
  a.x += w*x.x; a.y += w*x.y; a.z += w*x.z; a.w += w*x.w;
}

// ---------- transpose with dst stride: dst[c*S + r] = src[r*C + c] ----------
__global__ __launch_bounds__(256) void k_tr_s(const float* RI src, float* RI dst,
                                              int R, int C, int S){
  __shared__ float t[32][33];
  int tc0 = blockIdx.x*32, tr0 = blockIdx.y*32;
  int lx = threadIdx.x & 31, ly = threadIdx.x >> 5;
  for (int i = ly; i < 32; i += 8){
    int r = tr0 + i, c = tc0 + lx;
    t[i][lx] = (r < R && c < C) ? src[(long)r*C + c] : 0.f;
  }
  __syncthreads();
  for (int i = ly; i < 32; i += 8){
    int c = tc0 + i, r = tr0 + lx;
    if (c < C && r < R) dst[(long)c*S + r] = t[lx][i];
  }
}

// ---------- wih transpose with gate-interleaved permuted columns ----------
// WIHT[k][pc] = wih[j][k], pc = (j&511)*4 + (j>>9)
__global__ __launch_bounds__(256) void k_tr_wih(const float* RI src, float* RI ws){
  __shared__ float t[32][33];
  int tk0 = blockIdx.x*32, tj0 = blockIdx.y*32;
  int lx = threadIdx.x & 31, ly = threadIdx.x >> 5;
  for (int i = ly; i < 32; i += 8){
    int j = tj0 + i, k = tk0 + lx;
    t[i][lx] = src[(long)j*KX + k];
  }
  __syncthreads();
  for (int i = ly; i < 32; i += 8){
    int k = tk0 + i, j = tj0 + lx;
    int pc = ((j & 511) << 2) | (j >> 9);
    ws[O_WIHT + (long)k*G4 + pc] = t[lx][i];
  }
}

// ---------- meanT[f][b] ----------
__global__ __launch_bounds__(256) void k_mean(const float* RI feat, float* RI ws){
  int blk = blockIdx.x;             // 160 = 32 b x 5 f-tiles
  int b = blk / 5, ft = blk % 5;
  int f = ft*256 + threadIdx.x;
  float s = 0.f;
  const float* fp = feat + (long)b*Pn*Fn + f;
  for (int p = 0; p < Pn; ++p) s += fp[(long)p*Fn];
  ws[O_MEANT + (long)f*Bn + b] = s * (1.0f/Pn);
}

// ---------- h0,c0 ----------
__global__ __launch_bounds__(512) void k_h0c0(const float* RI ihb, const float* RI icb,
                                              float* RI ws){
  int tid = threadIdx.x;
  int jl = tid & 63, bq = tid >> 6;
  int j = blockIdx.x*64 + jl;
  const float* wp = ws + O_IHCT + j;
  const float* xp = ws + O_MEANT + bq*4;
  float4 acc = make_float4(0,0,0,0);
  for (int k = 0; k < Fn; ++k){
    float w = wp[(long)k*1024];
    float4 x = *(const float4*)(xp + (long)k*Bn);
    fma4(acc, x, w);
  }
  float va[4] = {acc.x, acc.y, acc.z, acc.w};
  if (j < Hn){
    float bias = ihb[j];
    #pragma unroll
    for (int m = 0; m < 4; ++m){
      int b = bq*4 + m;
      float v = va[m] + bias;
      ws[O_H  + (long)b*Hn + j] = v;
      ws[O_HT + (long)j*Bn + b] = v;
    }
  } else {
    int j2 = j - Hn;
    float bias = icb[j2];
    #pragma unroll
    for (int m = 0; m < 4; ++m)
      ws[O_C + (long)(bq*4+m)*Hn + j2] = va[m] + bias;
  }
}

// ---------- enc_proj ----------
__global__ __launch_bounds__(512) void k_encproj(const float* RI feat, const float* RI w2b,
                                                 float* RI ws){
  __shared__ float ft[32*65];
  int rt = blockIdx.x >> 3, ct = blockIdx.x & 7;
  int r0 = rt*64, j0 = ct*64;
  int tid = threadIdx.x;
  int jl = tid & 63, ro = tid >> 6;
  int j = j0 + jl;
  float acc[8] = {0,0,0,0,0,0,0,0};
  const float* w2t = ws + O_W2T;
  for (int k0 = 0; k0 < Fn; k0 += 32){
    int lr = tid >> 3, kq = tid & 7;
    float4 v = *(const float4*)(feat + (long)(r0+lr)*Fn + k0 + kq*4);
    ft[(kq*4+0)*65 + lr] = v.x; ft[(kq*4+1)*65 + lr] = v.y;
    ft[(kq*4+2)*65 + lr] = v.z; ft[(kq*4+3)*65 + lr] = v.w;
    __syncthreads();
    for (int kk = 0; kk < 32; ++kk){
      float w = w2t[(long)(k0+kk)*Hn + j];
      const float* fb = ft + kk*65 + ro*8;
      #pragma unroll
      for (int m = 0; m < 8; ++m) acc[m] += w * fb[m];
    }
    __syncthreads();
  }
  float bias = w2b[j];
  #pragma unroll
  for (int m = 0; m < 8; ++m)
    ws[O_ENC + (long)(r0 + ro*8 + m)*Hn + j] = acc[m] + bias;
}

// ---------- K1: unified h-GEMM, k-split waves. 217 blocks x 512 thr ----------
__global__ __launch_bounds__(512) void k_step1(
    const float* RI w1b, const float* RI gb, const float* RI bih, const float* RI bhh,
    const float* RI outb, float* RI ws, float* RI dout, int t)
{
  __shared__ float4 P4[8*512];      // 64 KB partials [bq][wv*64+jl]
  const int blk = blockIdx.x, tid = threadIdx.x;
  const int jl = tid & 63, wv = tid >> 6;
  if (t == Tn){
    if (blk < 2){
      const float* src = ws + (blk == 0 ? O_H : O_C);
      float* dst = dout + (long)Bn*Tn*Vn + (long)blk*Bn*Hn;
      for (int i = tid; i < Bn*Hn; i += 512) dst[i] = src[i];
    }
    if (blk < 60) return;
  } else if (blk >= 60 && t == 0) return;

  const int j = blk*64 + jl;
  const float* wp = ws + O_WCAT + j;
  float4 acc[8];
  #pragma unroll
  for (int q = 0; q < 8; ++q) acc[q] = make_float4(0,0,0,0);
  const int kb = wv*64;
  for (int k = kb; k < kb + 64; ++k){
    float w = wp[(long)k*NCAT];
    const float4* xr = (const float4*)(ws + O_HT + (long)k*Bn);
    #pragma unroll
    for (int q = 0; q < 8; ++q) fma4(acc[q], xr[q], w);
  }
  #pragma unroll
  for (int q = 0; q < 8; ++q) P4[q*512 + wv*64 + jl] = acc[q];
  __syncthreads();
  const int bq = wv;
  float4 s = make_float4(0,0,0,0);
  #pragma unroll
  for (int w = 0; w < 8; ++w){
    float4 p = P4[bq*512 + w*64 + jl];
    s.x += p.x; s.y += p.y; s.z += p.z; s.w += p.w;
  }

  if (blk < 8){                      // hid
    float bias = w1b[j];
    ws[O_HID + (long)(bq*4+0)*Hn + j] = s.x + bias;
    ws[O_HID + (long)(bq*4+1)*Hn + j] = s.y + bias;
    ws[O_HID + (long)(bq*4+2)*Hn + j] = s.z + bias;
    ws[O_HID + (long)(bq*4+3)*Hn + j] = s.w + bias;
  } else if (blk < 28){              // gate
    int f = j - J_GATE;
    float bias = gb[f];
    float4 g = make_float4(sigm(s.x+bias), sigm(s.y+bias),
                           sigm(s.z+bias), sigm(s.w+bias));
    *(float4*)(ws + O_GT + (long)f*Bn + bq*4) = g;
  } else if (blk < 60){              // xpart (permuted col layout)
    int j2 = j - J_XP;
    int pc = ((j2 & 511) << 2) | (j2 >> 9);
    float bias = bih[j2] + bhh[j2];
    float4 a = make_float4(s.x+bias, s.y+bias, s.z+bias, s.w+bias);
    *(float4*)(ws + O_XPT + (long)pc*Bn + bq*4) = a;
  } else {                           // logits_{t-1} + argmax partials
    int v = j - J_LOG;
    float lv[4];
    if (v < Vn){
      float bias = outb[v];
      lv[0]=s.x+bias; lv[1]=s.y+bias; lv[2]=s.z+bias; lv[3]=s.w+bias;
      #pragma unroll
      for (int m = 0; m < 4; ++m)
        dout[((long)(bq*4+m)*Tn + (t-1))*Vn + v] = lv[m];
    } else {
      lv[0]=lv[1]=lv[2]=lv[3]=-1e30f;
    }
    int tile = blk - 60;
    #pragma unroll
    for (int m = 0; m < 4; ++m){
      float bv = lv[m]; int bi = v;
      #pragma unroll
      for (int off = 32; off; off >>= 1){
        float ov = __shfl_down(bv, off, 64);
        int   oi = __shfl_down(bi, off, 64);
        if (ov > bv || (ov == bv && oi < bi)){ bv = ov; bi = oi; }
      }
      if (jl == 0){
        int b = bq*4 + m;
        ws[O_PMV + (long)b*NVT + tile] = bv;
        ((int*)(ws + O_PMI))[(long)b*NVT + tile] = bi;
      }
    }
  }
}

// ---------- K2: attention + xT build. 64 blocks x 512 thr ----------
// blocks 0-31: scores/softmax/ctx for b   blocks 32-63: argmax finalize + emb gather
__global__ __launch_bounds__(512) void k_attn(
    const float* RI vaw, const float* RI vab, const float* RI feat, const float* RI emb,
    float* RI ws, float* RI dout, int t)
{
  __shared__ float hid_s[512];
  __shared__ float sval[256];
  __shared__ float wts_s[256];
  __shared__ float inv_s;
  __shared__ int sel_s;
  const int blk = blockIdx.x, tid = threadIdx.x;

  if (blk < 32){
    const int b = blk;
    hid_s[tid] = ws[O_HID + (long)b*Hn + tid];
    __syncthreads();
    {
      int w = tid >> 6, l = tid & 63;
      const float* eb = ws + O_ENC + (long)b*Pn*Hn;
      for (int p = w; p < Pn; p += 8){
        const float* er = eb + (long)p*Hn;
        float4 e0 = *(const float4*)(er + l*4);
        float4 e1 = *(const float4*)(er + 256 + l*4);
        float4 h0 = *(const float4*)(hid_s + l*4);
        float4 h1 = *(const float4*)(hid_s + 256 + l*4);
        float4 v0 = *(const float4*)(vaw + l*4);
        float4 v1 = *(const float4*)(vaw + 256 + l*4);
        float s = fmaxf(h0.x+e0.x,0.f)*v0.x + fmaxf(h0.y+e0.y,0.f)*v0.y
                + fmaxf(h0.z+e0.z,0.f)*v0.z + fmaxf(h0.w+e0.w,0.f)*v0.w
                + fmaxf(h1.x+e1.x,0.f)*v1.x + fmaxf(h1.y+e1.y,0.f)*v1.y
                + fmaxf(h1.z+e1.z,0.f)*v1.z + fmaxf(h1.w+e1.w,0.f)*v1.w;
        #pragma unroll
        for (int off = 32; off; off >>= 1) s += __shfl_down(s, off, 64);
        if (l == 0) sval[p] = s + vab[0];
      }
    }
    __syncthreads();
    if (tid < 64){
      float m = -1e30f;
      for (int p = tid; p < Pn; p += 64) m = fmaxf(m, sval[p]);
      #pragma unroll
      for (int off = 32; off; off >>= 1) m = fmaxf(m, __shfl_xor(m, off, 64));
      float s = 0.f;
      for (int p = tid; p < Pn; p += 64){
        float e = expf(sval[p] - m);
        sval[p] = e; s += e;
      }
      #pragma unroll
      for (int off = 32; off; off >>= 1) s += __shfl_xor(s, off, 64);
      if (tid == 0) inv_s = 1.0f/s;
    }
    __syncthreads();
    if (tid < Pn){
      float wv = sval[tid] * inv_s;
      wts_s[tid] = wv;
      dout[(long)Bn*Tn*Vn + 2L*Bn*Hn + ((long)b*Tn + t)*Pn + tid] = wv;
    }
    __syncthreads();
    // ctx: f covered by tid, tid+512, tid+1024(<256)
    {
      const float* fb = feat + (long)b*Pn*Fn;
      float a0 = 0.f, a1 = 0.f, a2 = 0.f;
      for (int p = 0; p < Pn; ++p){
        float wv = wts_s[p];
        const float* fp = fb + (long)p*Fn;
        a0 += wv * fp[tid];
        a1 += wv * fp[tid + 512];
        if (tid < 256) a2 += wv * fp[tid + 1024];
      }
      a0 *= ws[O_GT + (long)tid*Bn + b];
      a1 *= ws[O_GT + (long)(tid+512)*Bn + b];
      ws[O_XT + (long)(En + tid)*Bn + b] = a0;
      ws[O_XT + (long)(En + tid + 512)*Bn + b] = a1;
      if (tid < 256){
        a2 *= ws[O_GT + (long)(tid+1024)*Bn + b];
        ws[O_XT + (long)(En + tid + 1024)*Bn + b] = a2;
      }
    }
  } else {
    const int b = blk - 32;
    if (t == 0){
      if (tid == 0) sel_s = 1;           // SOS
    } else if (tid < 64){
      float bv = -1e30f; int bi = 0x7fffffff;
      for (int q = tid; q < NVT; q += 64){
        float cv = ws[O_PMV + (long)b*NVT + q];
        if (cv > bv){ bv = cv; bi = ((const int*)(ws + O_PMI))[(long)b*NVT + q]; }
      }
      #pragma unroll
      for (int off = 32; off; off >>= 1){
        float ov = __shfl_down(bv, off, 64);
        int   oi = __shfl_down(bi, off, 64);
        if (ov > bv || (ov == bv && oi < bi)){ bv = ov; bi = oi; }
      }
      if (tid == 0) sel_s = bi;
    }
    __syncthreads();
    int row = sel_s;
    ws[O_XT + (long)tid*Bn + b] = emb[(long)row*En + tid];
  }
}

// ---------- K3: Wih GEMM (permuted cols) + LSTM update. 256 blocks x 256 thr ----------
__global__ __launch_bounds__(256) void k_gates(float* RI ws)
{
  __shared__ float red[4*16*16];    // [sk][c][b]
  __shared__ float gbuf[16*16];
  const int blk = blockIdx.x, tid = threadIdx.x;
  const int ct = blk >> 1, bh = blk & 1;
  const int c0 = ct*16;
  const int sk = tid >> 6, lane = tid & 63;
  const int cl = lane & 15, bs = lane >> 4;
  const float* wp = ws + O_WIHT + c0 + cl;
  const float* xp = ws + O_XT + bh*16 + bs*4;
  float4 acc = make_float4(0,0,0,0);
  const int kb = sk*448;
  for (int k = kb; k < kb + 448; ++k){
    float w = wp[(long)k*G4];
    float4 x = *(const float4*)(xp + (long)k*Bn);
    fma4(acc, x, w);
  }
  *(float4*)(red + (sk*16 + cl)*16 + bs*4) = acc;
  __syncthreads();
  {
    int c = tid >> 4, bl = tid & 15;
    float s = 0.f;
    #pragma unroll
    for (int q = 0; q < 4; ++q) s += red[(q*16 + c)*16 + bl];
    int pc = c0 + c;
    s += ws[O_XPT + (long)pc*Bn + bh*16 + bl];
    gbuf[c*16 + bl] = s;
  }
  __syncthreads();
  if (tid < 64){
    int il = tid >> 4, bl = tid & 15;
    int i = ct*4 + il, b = bh*16 + bl;
    float gi = gbuf[(il*4+0)*16 + bl];
    float gf = gbuf[(il*4+1)*16 + bl];
    float gg = gbuf[(il*4+2)*16 + bl];
    float go = gbuf[(il*4+3)*16 + bl];
    float c_ = ws[O_C + (long)b*Hn + i];
    float cn = sigm(gf)*c_ + sigm(gi)*tanhf(gg);
    float hn = sigm(go)*tanhf(cn);
    ws[O_C  + (long)b*Hn + i] = cn;
    ws[O_H  + (long)b*Hn + i] = hn;
    ws[O_HT + (long)i*Bn + b] = hn;
  }
}

} // anonymous namespace

extern "C" void kernel_launch(void* const* d_in, const int* in_sizes, int n_in,
                              void* d_out, int out_size, void* d_ws, size_t ws_size,
                              hipStream_t stream)
{
  (void)in_sizes; (void)n_in; (void)out_size; (void)ws_size;
  const float* feat = (const float*)d_in[0];
  const float* emb  = (const float*)d_in[3];
  const float* w1w  = (const float*)d_in[4];
  const float* w1b  = (const float*)d_in[5];
  const float* w2w  = (const float*)d_in[6];
  const float* w2b  = (const float*)d_in[7];
  const float* vaw  = (const float*)d_in[8];
  const float* vab  = (const float*)d_in[9];
  const float* wih  = (const float*)d_in[10];
  const float* whh  = (const float*)d_in[11];
  const float* bih  = (const float*)d_in[12];
  const float* bhh  = (const float*)d_in[13];
  const float* outw = (const float*)d_in[14];
  const float* outb = (const float*)d_in[15];
  const float* ihw  = (const float*)d_in[16];
  const float* ihb  = (const float*)d_in[17];
  const float* icw  = (const float*)d_in[18];
  const float* icb  = (const float*)d_in[19];
  const float* gw   = (const float*)d_in[20];
  const float* gb   = (const float*)d_in[21];
  float* ws  = (float*)d_ws;
  float* out = (float*)d_out;

  // setup: transposes of ihw/icw into ENC alias, mean, h0/c0
  k_tr_s<<<dim3(40,16),  256, 0, stream>>>(ihw,  ws + O_IHCT,       Hn, Fn, 1024);
  k_tr_s<<<dim3(40,16),  256, 0, stream>>>(icw,  ws + O_IHCT + 512, Hn, Fn, 1024);
  k_mean<<<160, 256, 0, stream>>>(feat, ws);
  k_h0c0<<<16, 512, 0, stream>>>(ihb, icb, ws);
  // persistent weight transposes
  k_tr_s<<<dim3(16,16),  256, 0, stream>>>(w1w,  ws + O_WCAT,          Hn, Hn, NCAT);
  k_tr_s<<<dim3(16,40),  256, 0, stream>>>(gw,   ws + O_WCAT + J_GATE, Fn, Hn, NCAT);
  k_tr_s<<<dim3(16,64),  256, 0, stream>>>(whh,  ws + O_WCAT + J_XP,   G4, Hn, NCAT);
  k_tr_s<<<dim3(16,313), 256, 0, stream>>>(outw, ws + O_WCAT + J_LOG,  Vn, Hn, NCAT);
  k_tr_wih<<<dim3(56,64), 256, 0, stream>>>(wih, ws);
  k_tr_s<<<dim3(40,16),  256, 0, stream>>>(w2w,  ws + O_W2T,           Hn, Fn, Hn);
  k_encproj<<<784, 512, 0, stream>>>(feat, w2b, ws);

  for (int t = 0; t < Tn; ++t){
    k_step1<<<217, 512, 0, stream>>>(w1b, gb, bih, bhh, outb, ws, out, t);
    k_attn <<< 64, 512, 0, stream>>>(vaw, vab, feat, emb, ws, out, t);
    k_gates<<<256, 256, 0, stream>>>(ws);
  }
  k_step1<<<217, 512, 0, stream>>>(w1b, gb, bih, bhh, outb, ws, out, Tn);
}